// Round 6
// baseline (240.630 us; speedup 1.0000x reference)
//
#include <hip/hip_runtime.h>
#include <math.h>

#define NB 16
#define NT 12
#define NN 2048
#define NH 16
#define NK 20

#define RPWV 4    // rows per wave; wave sweeps all 2048 nodes (32 tiles of 64)
#define CCAP 64

static __device__ __forceinline__ unsigned long long shflxor64(unsigned long long v, int m) {
  unsigned lo = (unsigned)v, hi = (unsigned)(v >> 32);
  lo = (unsigned)__shfl_xor((int)lo, m, 64);
  hi = (unsigned)__shfl_xor((int)hi, m, 64);
  return ((unsigned long long)hi << 32) | lo;
}

static __device__ __forceinline__ float rfl(float v) {
  return __int_as_float(__builtin_amdgcn_readfirstlane(__float_as_int(v)));
}

// one exact FMA order everywhere (pass A == pass B == gather == fallback):
static __device__ __forceinline__ float dotQ(const float* q, const float4& e0,
                                             const float4& e1, const float4& e2,
                                             const float4& e3) {
  float a = 0.0f;
  a = __fmaf_rn(q[0], e0.x, a);  a = __fmaf_rn(q[1], e0.y, a);
  a = __fmaf_rn(q[2], e0.z, a);  a = __fmaf_rn(q[3], e0.w, a);
  a = __fmaf_rn(q[4], e1.x, a);  a = __fmaf_rn(q[5], e1.y, a);
  a = __fmaf_rn(q[6], e1.z, a);  a = __fmaf_rn(q[7], e1.w, a);
  a = __fmaf_rn(q[8], e2.x, a);  a = __fmaf_rn(q[9], e2.y, a);
  a = __fmaf_rn(q[10], e2.z, a); a = __fmaf_rn(q[11], e2.w, a);
  a = __fmaf_rn(q[12], e3.x, a); a = __fmaf_rn(q[13], e3.y, a);
  a = __fmaf_rn(q[14], e3.z, a); a = __fmaf_rn(q[15], e3.w, a);
  return a;
}

// ---- kernel 0: state mean + 16-dim tanh embedding -------------------------
__global__ void k_emb(const float* __restrict__ x, const float* __restrict__ W,
                      const float* __restrict__ bias, float* __restrict__ emb) {
  int id = blockIdx.x * blockDim.x + threadIdx.x;
  if (id >= NB * NN) return;
  int b = id >> 11, n = id & (NN - 1);
  const float* xp = x + ((size_t)b * NT) * NN + n;
  float s = 0.0f;
#pragma unroll
  for (int t = 0; t < NT; ++t) s += xp[(size_t)t * NN];
  s = s / 12.0f;
  float* e = emb + (size_t)id * NH;
#pragma unroll
  for (int h = 0; h < NH; ++h) {
    float arg = __fadd_rn(__fmul_rn(s, W[h]), bias[h]);
    e[h] = (float)tanh((double)arg);
  }
}

// ---- kernel 1: A_physical row sums -> a / (sum + 1e-8) --------------------
__global__ void k_rowsum(const float* __restrict__ A, const float* __restrict__ alpha,
                         float* __restrict__ aInv) {
  int gw = (blockIdx.x * blockDim.x + threadIdx.x) >> 6;
  int lane = threadIdx.x & 63;
  if (gw >= NN) return;
  const float* row = A + (size_t)gw * NN;
  float s = 0.0f;
#pragma unroll
  for (int j = 0; j < NN / 64; ++j) s += row[lane + 64 * j];
#pragma unroll
  for (int off = 32; off; off >>= 1) s += __shfl_xor(s, off, 64);
  if (lane == 0) {
    float a = 1.0f / (1.0f + expf(-alpha[0]));
    aInv[gw] = a / (s + 1e-8f);
  }
}

// load one 64-node tile's worth for this lane (node = tile*64 + lane)
#define LDT(D, T)                                                   \
  {                                                                 \
    const float4* _p = ebase + (((T)*64 + lane) << 2);              \
    D##0 = _p[0]; D##1 = _p[1]; D##2 = _p[2]; D##3 = _p[3];         \
  }

// ---- kernel 2: two-pass streaming top-20 + softmax (idx, oma*w) -----------
// Wave = 4 rows x all 2048 nodes. 8192 waves -> 2048 blocks, no block sync.
__global__ __launch_bounds__(256, 6) void k_topk(
    const float* __restrict__ emb, const float* __restrict__ alpha,
    unsigned short* __restrict__ fixIdx, float* __restrict__ fixVal) {
  __shared__ unsigned short candIdx[4][RPWV][CCAP];   // 2 KB
  __shared__ unsigned long long fsel[4][NK];

  const int lane = threadIdx.x & 63;
  const int wv = threadIdx.x >> 6;
  const int gw = blockIdx.x * 4 + wv;     // wave id 0..8191
  const int b = gw >> 9;                  // 512 waves per batch
  const int rbase = (gw & 511) * RPWV;
  const float* embB = emb + (size_t)b * NN * NH;
  const float4* ebase = (const float4*)embB;

  // ---- query embeddings -> wave-uniform scalars (SGPRs) ----
  float qs[RPWV][NH];
#pragma unroll
  for (int r = 0; r < RPWV; ++r) {
    const float* qp = embB + (size_t)(rbase + r) * NH;
    float4 t0 = *(const float4*)(qp + 0),  t1 = *(const float4*)(qp + 4),
           t2 = *(const float4*)(qp + 8),  t3 = *(const float4*)(qp + 12);
    qs[r][0] = rfl(t0.x);  qs[r][1] = rfl(t0.y);  qs[r][2] = rfl(t0.z);  qs[r][3] = rfl(t0.w);
    qs[r][4] = rfl(t1.x);  qs[r][5] = rfl(t1.y);  qs[r][6] = rfl(t1.z);  qs[r][7] = rfl(t1.w);
    qs[r][8] = rfl(t2.x);  qs[r][9] = rfl(t2.y);  qs[r][10] = rfl(t2.z); qs[r][11] = rfl(t2.w);
    qs[r][12] = rfl(t3.x); qs[r][13] = rfl(t3.y); qs[r][14] = rfl(t3.z); qs[r][15] = rfl(t3.w);
  }

  // ---- pass A: pipelined sweep, per-lane running max over 32 tiles ----
  float rmax[RPWV];
#pragma unroll
  for (int r = 0; r < RPWV; ++r) rmax[r] = -1.0f;

  {
    float4 A0, A1, A2, A3, B0, B1, B2, B3;
    LDT(A, 0)
#pragma unroll 1
    for (int t = 0; t < 15; ++t) {
      LDT(B, 2 * t + 1)
#pragma unroll
      for (int r = 0; r < RPWV; ++r)
        rmax[r] = fmaxf(rmax[r], fmaxf(dotQ(qs[r], A0, A1, A2, A3), 0.0f));
      LDT(A, 2 * t + 2)
#pragma unroll
      for (int r = 0; r < RPWV; ++r)
        rmax[r] = fmaxf(rmax[r], fmaxf(dotQ(qs[r], B0, B1, B2, B3), 0.0f));
    }
    LDT(B, 31)
#pragma unroll
    for (int r = 0; r < RPWV; ++r)
      rmax[r] = fmaxf(rmax[r], fmaxf(dotQ(qs[r], A0, A1, A2, A3), 0.0f));
#pragma unroll
    for (int r = 0; r < RPWV; ++r)
      rmax[r] = fmaxf(rmax[r], fmaxf(dotQ(qs[r], B0, B1, B2, B3), 0.0f));
  }

  // ---- thresholds: th[r] = 20th largest of 64 lane-maxes (<= v20) ----
  float th[RPWV];
#pragma unroll
  for (int r = 0; r < RPWV; ++r) {
    float v = rmax[r];
#pragma unroll
    for (int k = 2; k <= 64; k <<= 1) {
#pragma unroll
      for (int m = k >> 1; m > 0; m >>= 1) {
        float o = __shfl_xor(v, m, 64);
        bool up = (lane & k) != 0;
        bool takeMax = ((lane & m) == 0) ^ up;
        v = takeMax ? fmaxf(v, o) : fminf(v, o);
      }
    }
    th[r] = rfl(__shfl(v, 19, 64));
  }

  // ---- pass B: identical pipelined sweep, build per-lane hit bitmask ----
  unsigned hm[RPWV];
#pragma unroll
  for (int r = 0; r < RPWV; ++r) hm[r] = 0u;

  {
    float4 A0, A1, A2, A3, B0, B1, B2, B3;
    LDT(A, 0)
#pragma unroll 1
    for (int t = 0; t < 15; ++t) {
      LDT(B, 2 * t + 1)
#pragma unroll
      for (int r = 0; r < RPWV; ++r) {
        float d = fmaxf(dotQ(qs[r], A0, A1, A2, A3), 0.0f);
        hm[r] |= (d >= th[r]) ? (1u << (2 * t)) : 0u;
      }
      LDT(A, 2 * t + 2)
#pragma unroll
      for (int r = 0; r < RPWV; ++r) {
        float d = fmaxf(dotQ(qs[r], B0, B1, B2, B3), 0.0f);
        hm[r] |= (d >= th[r]) ? (1u << (2 * t + 1)) : 0u;
      }
    }
    LDT(B, 31)
#pragma unroll
    for (int r = 0; r < RPWV; ++r) {
      float d = fmaxf(dotQ(qs[r], A0, A1, A2, A3), 0.0f);
      hm[r] |= (d >= th[r]) ? (1u << 30) : 0u;
    }
#pragma unroll
    for (int r = 0; r < RPWV; ++r) {
      float d = fmaxf(dotQ(qs[r], B0, B1, B2, B3), 0.0f);
      hm[r] |= (d >= th[r]) ? (1u << 31) : 0u;
    }
  }

  // ---- per-row: compact candidates, exact sort, softmax, write fixes ----
  float a_sig = 1.0f / (1.0f + expf(-alpha[0]));
  float oma = 1.0f - a_sig;

#pragma unroll 1
  for (int r = 0; r < RPWV; ++r) {
    const int row = rbase + r;

    // wave prefix-sum compaction of hit bitmasks into candIdx
    unsigned m = hm[r];
    int c = __popc(m);
    int pre = c;
#pragma unroll
    for (int off = 1; off < 64; off <<= 1) {
      int o = __shfl_up(pre, off, 64);
      if (lane >= off) pre += o;
    }
    int cnt = __builtin_amdgcn_readfirstlane(__shfl(pre, 63, 64));
    int pos = pre - c;
    while (m) {
      int j = __ffs(m) - 1;
      m &= m - 1;
      if (pos < CCAP) candIdx[wv][r][pos] = (unsigned short)((j << 6) | lane);
      ++pos;
    }
    asm volatile("s_waitcnt lgkmcnt(0)" ::: "memory");

    unsigned long long key = 0ull;
    if (cnt <= CCAP) {
      if (lane < cnt) {
        unsigned ci = candIdx[wv][r][lane];
        const float* ep = embB + (size_t)ci * NH;
        float4 e0 = *(const float4*)(ep + 0), e1 = *(const float4*)(ep + 4),
               e2 = *(const float4*)(ep + 8), e3 = *(const float4*)(ep + 12);
        float dd = fmaxf(dotQ(qs[r], e0, e1, e2, e3), 0.0f);
        key = ((unsigned long long)__float_as_uint(dd) << 32) | (unsigned)(~ci);
      }
#pragma unroll
      for (int k = 2; k <= 64; k <<= 1) {
#pragma unroll
        for (int mm = k >> 1; mm > 0; mm >>= 1) {
          unsigned long long o = shflxor64(key, mm);
          bool up = (lane & k) != 0;
          bool takeMax = ((lane & mm) == 0) ^ up;
          key = (takeMax == (key > o)) ? key : o;
        }
      }
    } else {
      // rare exact fallback (flat/tied rows): 20x wave argmax with recompute
      unsigned taken = 0u;
#pragma unroll 1
      for (int sel = 0; sel < NK; ++sel) {
        float bv = -1.0f;
        int bs = 0;
#pragma unroll 1
        for (int s = 0; s < 32; ++s) {
          const float* ep = embB + (size_t)(s * 64 + lane) * NH;
          float4 e0 = *(const float4*)(ep + 0), e1 = *(const float4*)(ep + 4),
                 e2 = *(const float4*)(ep + 8), e3 = *(const float4*)(ep + 12);
          float dd = fmaxf(dotQ(qs[r], e0, e1, e2, e3), 0.0f);
          bool ok = ((taken >> s) & 1u) == 0u;
          bool bet = ok && (dd > bv);
          bv = bet ? dd : bv;
          bs = bet ? s : bs;
        }
        unsigned idx = (unsigned)(bs * 64 + lane);
        unsigned long long kk = ((unsigned long long)__float_as_uint(bv) << 32) | (unsigned)(~idx);
#pragma unroll
        for (int off = 32; off; off >>= 1) {
          unsigned long long o = shflxor64(kk, off);
          kk = (o > kk) ? o : kk;
        }
        unsigned wi = ~(unsigned)kk;
        if ((wi & 63u) == (unsigned)lane) taken |= (1u << (wi >> 6));
        if (lane == 0) fsel[wv][sel] = kk;
      }
      asm volatile("s_waitcnt lgkmcnt(0)" ::: "memory");
      key = (lane < NK) ? fsel[wv][lane] : 0ull;
    }

    // softmax over selected (desc-sorted; lanes 0..19 hold top-20; cnt>=20 always)
    float vs = __uint_as_float((unsigned)(key >> 32));
    float vmax = __shfl(vs, 0, 64);
    float ex = (lane < NK) ? expf(vs - vmax) : 0.0f;
    float ssum = ex;
#pragma unroll
    for (int off = 32; off; off >>= 1) ssum += __shfl_xor(ssum, off, 64);
    if (lane < NK) {
      float w = ex / ssum;
      size_t o20 = ((size_t)b * NN + row) * NK + lane;
      fixVal[o20] = __fmul_rn(oma, w);          // k_out adds this to the base
      fixIdx[o20] = (unsigned short)(~(unsigned)key);
    }
  }
}

// ---- kernel 3: streaming output write + in-place sparse fix ---------------
__global__ __launch_bounds__(256, 6) void k_out(
    const float* __restrict__ Ap, const float* __restrict__ aInv,
    const unsigned short* __restrict__ fixIdx, const float* __restrict__ fixVal,
    float* __restrict__ out) {
  const int tid = threadIdx.x;
  const int lane = tid & 63;
  const int q = tid >> 6;
  const int n = blockIdx.x;

  float ai = aInv[n];
  const float4* pr = (const float4*)(Ap + (size_t)n * NN);
  float4 o[8];
#pragma unroll
  for (int f = 0; f < 8; ++f) {
    float4 p = pr[lane + 64 * f];
    o[f].x = __fmul_rn(p.x, ai);
    o[f].y = __fmul_rn(p.y, ai);
    o[f].z = __fmul_rn(p.z, ai);
    o[f].w = __fmul_rn(p.w, ai);
  }

  unsigned short ii[4];
  float vv[4];
#pragma unroll
  for (int i = 0; i < 4; ++i) {
    int bb = q * 4 + i;
    if (lane < NK) {
      size_t o20 = ((size_t)bb * NN + n) * NK + lane;
      ii[i] = fixIdx[o20];
      vv[i] = fixVal[o20];
    }
  }

#pragma unroll
  for (int i = 0; i < 4; ++i) {
    int bb = q * 4 + i;
    float4* orow = (float4*)(out + ((size_t)bb * NN + n) * NN);
#pragma unroll
    for (int f = 0; f < 8; ++f) orow[lane + 64 * f] = o[f];
  }
  // drain this wave's dense stores, then read back the 20 base values (L2-hot)
  asm volatile("s_waitcnt vmcnt(0)" ::: "memory");
#pragma unroll
  for (int i = 0; i < 4; ++i) {
    if (lane < NK) {
      int bb = q * 4 + i;
      size_t oo = ((size_t)bb * NN + n) * NN + (unsigned)ii[i];
      float base = out[oo];                 // == Ap[n][mi]*ai, just stored
      out[oo] = __fadd_rn(base, vv[i]);     // identical rounding to fused path
    }
  }
}

extern "C" void kernel_launch(void* const* d_in, const int* in_sizes, int n_in,
                              void* d_out, int out_size, void* d_ws, size_t ws_size,
                              hipStream_t stream) {
  const float* x = (const float*)d_in[0];
  const float* Ap = (const float*)d_in[1];
  const float* W = (const float*)d_in[2];
  const float* bb = (const float*)d_in[3];
  const float* alpha = (const float*)d_in[4];
  float* out = (float*)d_out;

  float* emb = (float*)d_ws;                                  // 2 MB
  float* aInv = emb + (size_t)NB * NN * NH;                   // 8 KB
  float* fixVal = aInv + NN;                                  // 2.62 MB
  unsigned short* fixIdx = (unsigned short*)(fixVal + (size_t)NB * NN * NK);  // 1.31 MB

  hipLaunchKernelGGL(k_emb, dim3((NB * NN + 255) / 256), dim3(256), 0, stream,
                     x, W, bb, emb);
  hipLaunchKernelGGL(k_rowsum, dim3((NN * 64) / 256), dim3(256), 0, stream,
                     Ap, alpha, aInv);
  hipLaunchKernelGGL(k_topk, dim3(NB * NN / (4 * RPWV)), dim3(256), 0, stream,
                     emb, alpha, fixIdx, fixVal);
  hipLaunchKernelGGL(k_out, dim3(NN), dim3(256), 0, stream,
                     Ap, aInv, fixIdx, fixVal, out);
}